// Round 1
// baseline (15757.474 us; speedup 1.0000x reference)
//
#include <hip/hip_runtime.h>
#include <stdint.h>
#include <stddef.h>

#define VOCAB  128
#define HIDDEN 1024
#define BATCH  64
#define SEQ    512

#define NGROUP 4      // batch groups
#define BG     16     // batches per group
#define NWG    64     // workgroups per group (column slices)
#define CJ     16     // W_hh columns per WG
#define NTHR   256

// ws layout in floats
#define E2_OFF   0          // [128][1024]
#define WOT_OFF  131072     // [128][1024]
#define HP_OFF   262144     // [2][64][1024] ping-pong h
#define BAR_OFF  393216     // int counters, 64 ints apart per group

#define USE_GLDS 1

// ---------------- E2 = emb @ W_hx + b_hx  ([128][1024]) ----------------
__global__ void e2_kernel(const float* __restrict__ emb, const float* __restrict__ W_hx,
                          const float* __restrict__ b_hx, float* __restrict__ E2) {
    int v = blockIdx.x >> 2;
    int j = (blockIdx.x & 3) * 256 + threadIdx.x;
    const float* er = emb + (size_t)v * HIDDEN;
    float acc = 0.f;
#pragma unroll 8
    for (int k = 0; k < HIDDEN; ++k)
        acc += er[k] * W_hx[(size_t)k * HIDDEN + j];
    E2[(size_t)v * HIDDEN + j] = acc + b_hx[j];
}

// ---------------- WoT[v][k] = W_out[k][v] ----------------
__global__ void wot_kernel(const float* __restrict__ W_out, float* __restrict__ WoT) {
    int v  = blockIdx.x;
    int k4 = threadIdx.x;           // 256 threads * 4 k each = 1024
    float4 r;
    r.x = W_out[(size_t)(k4*4+0)*VOCAB + v];
    r.y = W_out[(size_t)(k4*4+1)*VOCAB + v];
    r.z = W_out[(size_t)(k4*4+2)*VOCAB + v];
    r.w = W_out[(size_t)(k4*4+3)*VOCAB + v];
    ((float4*)(WoT + (size_t)v * HIDDEN))[k4] = r;
}

// ---------------- staging: global row -> LDS row, 16B-chunk XOR swizzle ----------------
// storage chunk cd of row r holds logical chunk (cd ^ (r&7)); done by pre-swizzling the
// per-lane GLOBAL source address (global_load_lds dest is wave-uniform base + lane*16).
__device__ __forceinline__ void stage_rows(const float* src, float* sH, int wv, int lane) {
    for (int r = wv * 4; r < wv * 4 + 4; ++r) {
        const float* rowg = src + (size_t)r * HIDDEN;
        int rx = r & 7;
#pragma unroll
        for (int i = 0; i < 4; ++i) {
            int cd = i * 64 + lane;
            int cs = cd ^ rx;
#if USE_GLDS
            __builtin_amdgcn_global_load_lds(
                (const __attribute__((address_space(1))) void*)(rowg + cs * 4),
                (__attribute__((address_space(3))) void*)(sH + (size_t)r * HIDDEN + i * 256),
                16, 0, 0);
#else
            float4 vv = *(const float4*)(rowg + cs * 4);
            *(float4*)(sH + (size_t)r * HIDDEN + cd * 4) = vv;
#endif
        }
    }
}

// ---------------- fused logits slice: logits[b][tprev][2w..2w+1] from staged sH ----------------
__device__ __forceinline__ void logits_phase(const float* sH, const float* WoT,
                                             const float* b_out, float* logits,
                                             int b0, int w, int tprev, int tid) {
    int b = tid >> 4, kz = tid & 15;
    int bx = b & 7;
    const float4* sHf = (const float4*)(sH + (size_t)b * HIDDEN);
    const float4* w0  = (const float4*)(WoT + (size_t)(2*w)   * HIDDEN);
    const float4* w1  = (const float4*)(WoT + (size_t)(2*w+1) * HIDDEN);
    float a0 = 0.f, a1 = 0.f;
#pragma unroll 4
    for (int m = 0; m < 16; ++m) {
        int c = kz + 16 * m;                 // logical chunk; k = 4*c
        float4 h4 = sHf[c ^ bx];
        float4 u  = w0[c];
        float4 vv = w1[c];
        a0 += h4.x*u.x  + h4.y*u.y  + h4.z*u.z  + h4.w*u.w;
        a1 += h4.x*vv.x + h4.y*vv.y + h4.z*vv.z + h4.w*vv.w;
    }
#pragma unroll
    for (int off = 1; off < 16; off <<= 1) {
        a0 += __shfl_xor(a0, off);
        a1 += __shfl_xor(a1, off);
    }
    if (kz == 0) {
        float* lp = logits + ((size_t)(b0 + b) * SEQ + tprev) * VOCAB + 2 * w;
        lp[0] = a0 + b_out[2*w];
        lp[1] = a1 + b_out[2*w + 1];
    }
}

// ---------------- persistent recurrence kernel ----------------
// grid = 256 blocks (4 groups x 64 col-slices), 256 threads, 128KB dynamic LDS -> 1 WG/CU.
extern "C" __global__ void __launch_bounds__(NTHR, 1)
rnn_kernel(const int* __restrict__ x, const float* __restrict__ h0,
           const float* __restrict__ W_hh,
           const float* __restrict__ E2, const float* __restrict__ WoT,
           const float* __restrict__ b_out,
           float* __restrict__ hP, int* __restrict__ bar,
           float* __restrict__ logits, float* __restrict__ hf) {
    extern __shared__ float lds[];
    float* sW = lds;                         // [CJ][1024] f32, chunk-swizzled by (j&7)
    float* sH = lds + (size_t)CJ * HIDDEN;   // [BG][1024] f32, chunk-swizzled by (b&7)
    float* part = sH;                        // 16KB overlay, used after FMA phase

    const int wg = blockIdx.x;
    const int g  = wg / NWG;
    const int w  = wg % NWG;
    const int b0 = g * BG;
    const int j0 = w * CJ;
    const int tid  = threadIdx.x;
    const int lane = tid & 63;
    const int wv   = tid >> 6;
    int* barg = bar + g * 64;

    // ---- load W_hh column slice into LDS, transposed + swizzled ----
    {
        int j = tid & 15, kc = tid >> 4;
        for (int kk = 0; kk < 64; ++kk) {
            int k = kc * 64 + kk;
            float val = W_hh[(size_t)k * HIDDEN + j0 + j];
            int c = k >> 2, e = k & 3;
            sW[(size_t)j * HIDDEN + ((c ^ (j & 7)) << 2) + e] = val;
        }
    }
    __syncthreads();

    const int kz = tid >> 4;
    const int r_ = tid & 15;
    const int j2 = r_ >> 2, b2 = r_ & 3;
    const float4* sWf  = (const float4*)sW;
    const float4* sHf4 = (const float4*)sH;

    for (int t = 0; t < SEQ; ++t) {
        if (t > 0) {
            if (tid == 0) {
                int target = NWG * t, guard = 0;
                while (__hip_atomic_load(barg, __ATOMIC_RELAXED, __HIP_MEMORY_SCOPE_AGENT) < target
                       && ++guard < (1 << 24))
                    __builtin_amdgcn_s_sleep(2);
            }
            __syncthreads();
            __threadfence();   // acquire: invalidate stale L1/L2 before reading peer h
        }
        const float* src = (t == 0) ? (h0 + (size_t)b0 * HIDDEN)
                                    : (hP + (size_t)((t - 1) & 1) * BATCH * HIDDEN + (size_t)b0 * HIDDEN);
        stage_rows(src, sH, wv, lane);
        __syncthreads();   // drains global_load_lds (vmcnt) too

        if (t > 0)
            logits_phase(sH, WoT, b_out, logits, b0, w, t - 1, tid);

        // ---- main FMA phase: thread tile 4b x 4j, k-split 16 ways ----
        float acc[4][4];
#pragma unroll
        for (int ib = 0; ib < 4; ++ib)
#pragma unroll
            for (int jj = 0; jj < 4; ++jj) acc[ib][jj] = 0.f;

#pragma unroll 4
        for (int m = 0; m < 16; ++m) {
            int cb = kz + 16 * m;            // logical chunk; k = 4*cb
            float4 h4[4], w4[4];
#pragma unroll
            for (int ib = 0; ib < 4; ++ib) {
                int b = 4 * b2 + ib;
                h4[ib] = sHf4[(size_t)b * 256 + (cb ^ (b & 7))];
            }
#pragma unroll
            for (int jj = 0; jj < 4; ++jj) {
                int j = 4 * j2 + jj;
                w4[jj] = sWf[(size_t)j * 256 + (cb ^ (j & 7))];
            }
#pragma unroll
            for (int ib = 0; ib < 4; ++ib)
#pragma unroll
                for (int jj = 0; jj < 4; ++jj) {
                    acc[ib][jj] += h4[ib].x * w4[jj].x;
                    acc[ib][jj] += h4[ib].y * w4[jj].y;
                    acc[ib][jj] += h4[ib].z * w4[jj].z;
                    acc[ib][jj] += h4[ib].w * w4[jj].w;
                }
        }
        __syncthreads();   // all reads of sH done -> safe to overlay with partials

        // part[kz][b][j]
#pragma unroll
        for (int ib = 0; ib < 4; ++ib) {
            float4 pv = make_float4(acc[ib][0], acc[ib][1], acc[ib][2], acc[ib][3]);
            *(float4*)(part + (size_t)kz * 256 + (4 * b2 + ib) * 16 + 4 * j2) = pv;
        }
        __syncthreads();

        // ---- reduce + E2 lookup + tanh + write ----
        {
            int b = tid >> 4, j = tid & 15;
            float s = 0.f;
#pragma unroll
            for (int z = 0; z < 16; ++z) s += part[(size_t)z * 256 + tid];
            int xv = x[(size_t)(b0 + b) * SEQ + t];
            float val = s + E2[(size_t)xv * HIDDEN + j0 + j];
            float hn = tanhf(val);
            float* dst = hP + (size_t)(t & 1) * BATCH * HIDDEN;
            dst[(size_t)(b0 + b) * HIDDEN + j0 + j] = hn;
            if (t == SEQ - 1) hf[(size_t)(b0 + b) * HIDDEN + j0 + j] = hn;
        }
        __syncthreads();
        if (tid == 0) {
            __threadfence();          // release: flush L2 before signaling
            atomicAdd(barg, 1);
        }
    }

    // ---- epilogue: logits for t = SEQ-1 from h_SEQ ----
    if (tid == 0) {
        int guard = 0;
        while (__hip_atomic_load(barg, __ATOMIC_RELAXED, __HIP_MEMORY_SCOPE_AGENT) < NWG * SEQ
               && ++guard < (1 << 24))
            __builtin_amdgcn_s_sleep(2);
    }
    __syncthreads();
    __threadfence();
    stage_rows(hP + (size_t)((SEQ - 1) & 1) * BATCH * HIDDEN + (size_t)b0 * HIDDEN, sH, wv, lane);
    __syncthreads();
    logits_phase(sH, WoT, b_out, logits, b0, w, SEQ - 1, tid);
}

extern "C" void kernel_launch(void* const* d_in, const int* in_sizes, int n_in,
                              void* d_out, int out_size, void* d_ws, size_t ws_size,
                              hipStream_t stream) {
    (void)in_sizes; (void)n_in; (void)out_size; (void)ws_size;
    const int*   x     = (const int*)  d_in[0];
    const float* h0    = (const float*)d_in[1];
    const float* emb   = (const float*)d_in[2];
    const float* W_hx  = (const float*)d_in[3];
    const float* b_hx  = (const float*)d_in[4];
    const float* W_hh  = (const float*)d_in[5];
    const float* W_out = (const float*)d_in[6];
    const float* b_out = (const float*)d_in[7];

    float* logits = (float*)d_out;
    float* hf     = logits + (size_t)BATCH * SEQ * VOCAB;

    float* ws  = (float*)d_ws;
    float* E2  = ws + E2_OFF;
    float* WoT = ws + WOT_OFF;
    float* hP  = ws + HP_OFF;
    int*   bar = (int*)(ws + BAR_OFF);

    hipMemsetAsync(bar, 0, 1024, stream);
    e2_kernel<<<512, 256, 0, stream>>>(emb, W_hx, b_hx, E2);
    wot_kernel<<<128, 256, 0, stream>>>(W_out, WoT);

    hipFuncSetAttribute(reinterpret_cast<const void*>(rnn_kernel),
                        hipFuncAttributeMaxDynamicSharedMemorySize, 131072);
    rnn_kernel<<<NGROUP * NWG, NTHR, 131072, stream>>>(x, h0, W_hh, E2, WoT, b_out,
                                                       hP, bar, logits, hf);
}

// Round 2
// 3601.025 us; speedup vs baseline: 4.3758x; 4.3758x over previous
//
#include <hip/hip_runtime.h>
#include <stdint.h>
#include <stddef.h>

#define VOCAB  128
#define HIDDEN 1024
#define BATCH  64
#define SEQ    512

#define NGROUP 4      // batch groups
#define BG     16     // batches per group
#define NWG    64     // workgroups per group (column slices)
#define CJ     16     // W_hh columns per WG
#define NTHR   512

// ws layout in floats
#define E2_OFF   0          // [128][1024]
#define WOT_OFF  131072     // [128][1024]
#define HP_OFF   262144     // [2][64][1024] ping-pong h
#define BAR_OFF  393216     // int counters, 64 ints apart per group

// ---------------- coherent (cross-XCD) access helpers ----------------
// sc0 sc1 loads/stores bypass the per-XCD L2 and hit the die-level MALL,
// which IS shared across XCDs -> no cache-wide fences needed.
__device__ __forceinline__ float4 cload4(const float* p) {
    float4 v;
    asm volatile("global_load_dwordx4 %0, %1, off sc0 sc1" : "=v"(v) : "v"(p));
    return v;
}
__device__ __forceinline__ void cstore1(float* p, float x) {
    asm volatile("global_store_dword %0, %1, off sc0 sc1" :: "v"(p), "v"(x) : "memory");
}
#define WAITVM0() asm volatile("s_waitcnt vmcnt(0)" ::: "memory")

// ---------------- E2 = emb @ W_hx + b_hx  ([128][1024]) ----------------
__global__ void e2_kernel(const float* __restrict__ emb, const float* __restrict__ W_hx,
                          const float* __restrict__ b_hx, float* __restrict__ E2) {
    int v = blockIdx.x >> 2;
    int j = (blockIdx.x & 3) * 256 + threadIdx.x;
    const float* er = emb + (size_t)v * HIDDEN;
    float acc = 0.f;
#pragma unroll 8
    for (int k = 0; k < HIDDEN; ++k)
        acc += er[k] * W_hx[(size_t)k * HIDDEN + j];
    E2[(size_t)v * HIDDEN + j] = acc + b_hx[j];
}

// ---------------- WoT[v][k] = W_out[k][v] ----------------
__global__ void wot_kernel(const float* __restrict__ W_out, float* __restrict__ WoT) {
    int v  = blockIdx.x;
    int k4 = threadIdx.x;           // 256 threads * 4 k each = 1024
    float4 r;
    r.x = W_out[(size_t)(k4*4+0)*VOCAB + v];
    r.y = W_out[(size_t)(k4*4+1)*VOCAB + v];
    r.z = W_out[(size_t)(k4*4+2)*VOCAB + v];
    r.w = W_out[(size_t)(k4*4+3)*VOCAB + v];
    ((float4*)(WoT + (size_t)v * HIDDEN))[k4] = r;
}

// ---------------- staging: coherent global -> regs -> LDS (16B-chunk XOR swizzle) ----------------
// storage chunk s of row r holds logical chunk (s ^ (r&7)).
// 8 waves, 2 rows per wave, 4 chunks per lane.
__device__ __forceinline__ void stage_rows_coh(const float* src, float* sH, int wv, int lane) {
    float4 tmp[8];
#pragma unroll
    for (int q = 0; q < 2; ++q) {
        int r = wv * 2 + q;
        const float* rowg = src + (size_t)r * HIDDEN;
#pragma unroll
        for (int i = 0; i < 4; ++i) {
            int c = i * 64 + lane;
            tmp[q * 4 + i] = cload4(rowg + c * 4);
        }
    }
    WAITVM0();
    __builtin_amdgcn_sched_barrier(0);
#pragma unroll
    for (int q = 0; q < 2; ++q) {
        int r = wv * 2 + q;
        int rx = r & 7;
#pragma unroll
        for (int i = 0; i < 4; ++i) {
            int c = i * 64 + lane;
            *(float4*)(sH + (size_t)r * HIDDEN + (size_t)(c ^ rx) * 4) = tmp[q * 4 + i];
        }
    }
}

// ---------------- fused logits slice: logits[b][tprev][2w..2w+1] from staged sH ----------------
__device__ __forceinline__ void logits_phase(const float* sH, const float* WoT,
                                             const float* b_out, float* logits,
                                             int b0, int w, int tprev, int tid) {
    int b = tid >> 5, kz = tid & 31;     // 16 b x 32 k-threads
    int bx = b & 7;
    const float4* sHf = (const float4*)(sH + (size_t)b * HIDDEN);
    const float4* w0  = (const float4*)(WoT + (size_t)(2*w)   * HIDDEN);
    const float4* w1  = (const float4*)(WoT + (size_t)(2*w+1) * HIDDEN);
    float a0 = 0.f, a1 = 0.f;
#pragma unroll
    for (int m = 0; m < 8; ++m) {
        int c = kz + 32 * m;             // logical chunk; k = 4*c
        float4 h4 = sHf[c ^ bx];
        float4 u  = w0[c];
        float4 vv = w1[c];
        a0 += h4.x*u.x  + h4.y*u.y  + h4.z*u.z  + h4.w*u.w;
        a1 += h4.x*vv.x + h4.y*vv.y + h4.z*vv.z + h4.w*vv.w;
    }
#pragma unroll
    for (int off = 1; off < 32; off <<= 1) {
        a0 += __shfl_xor(a0, off);
        a1 += __shfl_xor(a1, off);
    }
    if (kz == 0) {
        float* lp = logits + ((size_t)(b0 + b) * SEQ + tprev) * VOCAB + 2 * w;
        lp[0] = a0 + b_out[2*w];
        lp[1] = a1 + b_out[2*w + 1];
    }
}

// ---------------- persistent recurrence kernel ----------------
// grid = 256 blocks (4 groups x 64 col-slices), 512 threads, 128KB dynamic LDS -> 1 WG/CU,
// 2 waves/SIMD.
extern "C" __global__ void __launch_bounds__(NTHR, 1)
rnn_kernel(const int* __restrict__ x, const float* __restrict__ h0,
           const float* __restrict__ W_hh,
           const float* __restrict__ E2, const float* __restrict__ WoT,
           const float* __restrict__ b_out,
           float* __restrict__ hP, int* __restrict__ bar,
           float* __restrict__ logits, float* __restrict__ hf) {
    extern __shared__ float lds[];
    float* sW = lds;                         // [CJ][1024] f32, chunk-swizzled by (j&7)
    float* sH = lds + (size_t)CJ * HIDDEN;   // [BG][1024] f32, chunk-swizzled by (b&7)
    float* part = sH;                        // 32KB overlay, used after FMA phase

    const int wg = blockIdx.x;
    const int g  = wg / NWG;
    const int w  = wg % NWG;
    const int b0 = g * BG;
    const int j0 = w * CJ;
    const int tid  = threadIdx.x;
    const int lane = tid & 63;
    const int wv   = tid >> 6;
    int* barg = bar + g * 64;

    // ---- load W_hh column slice into LDS, transposed + swizzled (once) ----
    {
        int j = tid & 15, kc = tid >> 4;     // kc in [0,32)
        for (int kk = 0; kk < 32; ++kk) {
            int k = kc * 32 + kk;
            float val = W_hh[(size_t)k * HIDDEN + j0 + j];
            int c = k >> 2, e = k & 3;
            sW[(size_t)j * HIDDEN + ((c ^ (j & 7)) << 2) + e] = val;
        }
    }
    __syncthreads();

    const int kz = tid >> 4;                 // [0,32) k-split
    const int r_ = tid & 15;
    const int j2 = r_ >> 2, b2 = r_ & 3;
    const float4* sWf  = (const float4*)sW;
    const float4* sHf4 = (const float4*)sH;

    for (int t = 0; t < SEQ; ++t) {
        if (t > 0) {
            if (tid == 0) {
                int target = NWG * t, guard = 0;
                while (__hip_atomic_load(barg, __ATOMIC_RELAXED, __HIP_MEMORY_SCOPE_AGENT) < target
                       && ++guard < (1 << 24))
                    __builtin_amdgcn_s_sleep(2);
            }
            __syncthreads();                 // no fence: h exchange is per-access coherent
        }
        const float* src = (t == 0) ? (h0 + (size_t)b0 * HIDDEN)
                                    : (hP + (size_t)((t - 1) & 1) * BATCH * HIDDEN + (size_t)b0 * HIDDEN);
        stage_rows_coh(src, sH, wv, lane);
        __syncthreads();

        if (t > 0)
            logits_phase(sH, WoT, b_out, logits, b0, w, t - 1, tid);

        // ---- main FMA phase: thread tile 4b x 4j, k-split 32 ways ----
        float acc[4][4];
#pragma unroll
        for (int ib = 0; ib < 4; ++ib)
#pragma unroll
            for (int jj = 0; jj < 4; ++jj) acc[ib][jj] = 0.f;

#pragma unroll
        for (int m = 0; m < 8; ++m) {
            int cb = kz + 32 * m;            // logical chunk; k = 4*cb
            float4 h4[4], w4[4];
#pragma unroll
            for (int ib = 0; ib < 4; ++ib) {
                int b = 4 * b2 + ib;
                h4[ib] = sHf4[(size_t)b * 256 + (cb ^ (b & 7))];
            }
#pragma unroll
            for (int jj = 0; jj < 4; ++jj) {
                int j = 4 * j2 + jj;
                w4[jj] = sWf[(size_t)j * 256 + (cb ^ (j & 7))];
            }
#pragma unroll
            for (int ib = 0; ib < 4; ++ib)
#pragma unroll
                for (int jj = 0; jj < 4; ++jj) {
                    acc[ib][jj] += h4[ib].x * w4[jj].x;
                    acc[ib][jj] += h4[ib].y * w4[jj].y;
                    acc[ib][jj] += h4[ib].z * w4[jj].z;
                    acc[ib][jj] += h4[ib].w * w4[jj].w;
                }
        }
        __syncthreads();   // all reads of sH done -> safe to overlay with partials

        // part[kz][b][j]  (32 x 256 floats = 32KB inside sH)
#pragma unroll
        for (int ib = 0; ib < 4; ++ib) {
            float4 pv = make_float4(acc[ib][0], acc[ib][1], acc[ib][2], acc[ib][3]);
            *(float4*)(part + (size_t)kz * 256 + (4 * b2 + ib) * 16 + 4 * j2) = pv;
        }
        __syncthreads();

        // ---- reduce + E2 lookup + tanh + coherent write ----
        if (tid < 256) {
            int b = tid >> 4, j = tid & 15;
            float s = 0.f;
#pragma unroll
            for (int z = 0; z < 32; ++z) s += part[(size_t)z * 256 + tid];
            int xv = x[(size_t)(b0 + b) * SEQ + t];
            float val = s + E2[(size_t)xv * HIDDEN + j0 + j];
            float hn = tanhf(val);
            float* dst = hP + (size_t)(t & 1) * BATCH * HIDDEN;
            cstore1(dst + (size_t)(b0 + b) * HIDDEN + j0 + j, hn);
            if (t == SEQ - 1) hf[(size_t)(b0 + b) * HIDDEN + j0 + j] = hn;
        }
        WAITVM0();         // own coherent stores reached the MALL
        __syncthreads();   // all threads' stores done
        if (tid == 0)
            __hip_atomic_fetch_add(barg, 1, __ATOMIC_RELAXED, __HIP_MEMORY_SCOPE_AGENT);
    }

    // ---- epilogue: logits for t = SEQ-1 from h_SEQ ----
    if (tid == 0) {
        int guard = 0;
        while (__hip_atomic_load(barg, __ATOMIC_RELAXED, __HIP_MEMORY_SCOPE_AGENT) < NWG * SEQ
               && ++guard < (1 << 24))
            __builtin_amdgcn_s_sleep(2);
    }
    __syncthreads();
    stage_rows_coh(hP + (size_t)((SEQ - 1) & 1) * BATCH * HIDDEN + (size_t)b0 * HIDDEN, sH, wv, lane);
    __syncthreads();
    logits_phase(sH, WoT, b_out, logits, b0, w, SEQ - 1, tid);
}

extern "C" void kernel_launch(void* const* d_in, const int* in_sizes, int n_in,
                              void* d_out, int out_size, void* d_ws, size_t ws_size,
                              hipStream_t stream) {
    (void)in_sizes; (void)n_in; (void)out_size; (void)ws_size;
    const int*   x     = (const int*)  d_in[0];
    const float* h0    = (const float*)d_in[1];
    const float* emb   = (const float*)d_in[2];
    const float* W_hx  = (const float*)d_in[3];
    const float* b_hx  = (const float*)d_in[4];
    const float* W_hh  = (const float*)d_in[5];
    const float* W_out = (const float*)d_in[6];
    const float* b_out = (const float*)d_in[7];

    float* logits = (float*)d_out;
    float* hf     = logits + (size_t)BATCH * SEQ * VOCAB;

    float* ws  = (float*)d_ws;
    float* E2  = ws + E2_OFF;
    float* WoT = ws + WOT_OFF;
    float* hP  = ws + HP_OFF;
    int*   bar = (int*)(ws + BAR_OFF);

    hipMemsetAsync(bar, 0, 1024, stream);
    e2_kernel<<<512, 256, 0, stream>>>(emb, W_hx, b_hx, E2);
    wot_kernel<<<128, 256, 0, stream>>>(W_out, WoT);

    hipFuncSetAttribute(reinterpret_cast<const void*>(rnn_kernel),
                        hipFuncAttributeMaxDynamicSharedMemorySize, 131072);
    rnn_kernel<<<NGROUP * NWG, NTHR, 131072, stream>>>(x, h0, W_hh, E2, WoT, b_out,
                                                       hP, bar, logits, hf);
}

// Round 3
// 2520.707 us; speedup vs baseline: 6.2512x; 1.4286x over previous
//
#include <hip/hip_runtime.h>
#include <stdint.h>
#include <stddef.h>

#define VOCAB  128
#define HIDDEN 1024
#define BATCH  64
#define SEQ    512

#define NGROUP 4      // batch groups
#define BG     16     // batches per group
#define NWG    32     // workgroups per group (column slices)
#define CJ     32     // W_hh columns per WG
#define NVW    4      // vocab rows per WG (VOCAB/NWG)
#define NTHR   512

// ws layout in float units
#define E2_OFF   0          // [128][1024] f32
#define WOT_OFF  131072     // [128][1024] f32
#define HPH_OFF  262144     // [2][64][1024] bf16 hi (65536 floats)
#define HPL_OFF  327680     // [2][64][1024] bf16 lo
#define FLG_OFF  393216     // int flags[NGROUP][32]

typedef __attribute__((ext_vector_type(8))) short short8_t;
typedef __attribute__((ext_vector_type(4))) float f32x4;

// ---------------- coherent (cross-XCD, MALL-level) access helpers ----------------
__device__ __forceinline__ uint4 cload4u(const void* p) {
    uint4 v;
    asm volatile("global_load_dwordx4 %0, %1, off sc0 sc1" : "=v"(v) : "v"(p));
    return v;
}
__device__ __forceinline__ int cloadi(const int* p) {
    int v;
    asm volatile("global_load_dword %0, %1, off sc0 sc1\n\ts_waitcnt vmcnt(0)"
                 : "=v"(v) : "v"(p) : "memory");
    return v;
}
__device__ __forceinline__ void cstore_short(void* p, unsigned int x) {
    asm volatile("global_store_short %0, %1, off sc0 sc1" :: "v"(p), "v"(x) : "memory");
}
#define WAITVM0() asm volatile("s_waitcnt vmcnt(0)" ::: "memory")

// ---------------- bf16 split helpers ----------------
__device__ __forceinline__ unsigned short bf16_rne(float f) {
    unsigned int u = __float_as_uint(f);
    u += 0x7FFF + ((u >> 16) & 1);
    return (unsigned short)(u >> 16);
}
__device__ __forceinline__ float bf16_f32(unsigned short h) {
    return __uint_as_float(((unsigned int)h) << 16);
}

// ---------------- E2 = emb @ W_hx + b_hx  ([128][1024]) ----------------
__global__ void e2_kernel(const float* __restrict__ emb, const float* __restrict__ W_hx,
                          const float* __restrict__ b_hx, float* __restrict__ E2) {
    int v = blockIdx.x >> 2;
    int j = (blockIdx.x & 3) * 256 + threadIdx.x;
    const float* er = emb + (size_t)v * HIDDEN;
    float acc = 0.f;
#pragma unroll 8
    for (int k = 0; k < HIDDEN; ++k)
        acc += er[k] * W_hx[(size_t)k * HIDDEN + j];
    E2[(size_t)v * HIDDEN + j] = acc + b_hx[j];
}

// ---------------- WoT[v][k] = W_out[k][v] ----------------
__global__ void wot_kernel(const float* __restrict__ W_out, float* __restrict__ WoT) {
    int v  = blockIdx.x;
    int k4 = threadIdx.x;
    float4 r;
    r.x = W_out[(size_t)(k4*4+0)*VOCAB + v];
    r.y = W_out[(size_t)(k4*4+1)*VOCAB + v];
    r.z = W_out[(size_t)(k4*4+2)*VOCAB + v];
    r.w = W_out[(size_t)(k4*4+3)*VOCAB + v];
    ((float4*)(WoT + (size_t)v * HIDDEN))[k4] = r;
}

// ---------------- persistent recurrence kernel ----------------
// grid = 128 blocks (4 groups x 32 col-slices), 512 threads (8 waves), 112KB LDS.
// LDS: sHi[16][1024] bf16 (chunk-swizzled), sLo same, sPart[8][512] f32, sX[16][512] int.
extern "C" __global__ void __launch_bounds__(NTHR, 2)
rnn_kernel(const int* __restrict__ x, const float* __restrict__ h0,
           const float* __restrict__ W_hh,
           const float* __restrict__ E2, const float* __restrict__ WoT,
           const float* __restrict__ b_out,
           unsigned short* __restrict__ hpHi, unsigned short* __restrict__ hpLo,
           int* __restrict__ flags,
           float* __restrict__ logits, float* __restrict__ hf) {
    extern __shared__ char lds_raw[];
    short* sHi  = (short*)lds_raw;                    // 16*1024 bf16 = 32KB
    short* sLo  = sHi + 16 * 1024;                    // 32KB
    float* sPart = (float*)(sLo + 16 * 1024);         // 8*512 f32 = 16KB
    int*   sX   = (int*)(sPart + 8 * 512);            // 16*512 int = 32KB

    const int wg = blockIdx.x;
    const int g  = wg / NWG;
    const int w  = wg % NWG;
    const int b0 = g * BG;
    const int j0 = w * CJ;
    const int tid  = threadIdx.x;
    const int lane = tid & 63;
    const int wv   = tid >> 6;
    int* flg = flags + g * 32;

    // ---- prologue: x slice -> LDS ----
    {
        const int4* xs4 = (const int4*)(x + (size_t)b0 * SEQ);
#pragma unroll
        for (int i = 0; i < 4; ++i)
            ((int4*)sX)[tid + 512 * i] = xs4[tid + 512 * i];
    }

    // ---- prologue: W_hh column slice -> bf16 hi/lo fragments in VGPRs ----
    // wave wv owns k in [wv*128, wv*128+128); B-frag: lane l holds B[k=(l>>4)*8+e][col=l&15]
    short8_t whi[2][4], wlo[2][4];
    {
        const int colb = lane & 15, kgrp = lane >> 4;
#pragma unroll
        for (int ct = 0; ct < 2; ++ct) {
            int col = j0 + ct * 16 + colb;
#pragma unroll
            for (int c = 0; c < 4; ++c) {
                int kb = wv * 128 + c * 32 + kgrp * 8;
#pragma unroll
                for (int e = 0; e < 8; ++e) {
                    float wval = W_hh[(size_t)(kb + e) * HIDDEN + col];
                    unsigned short hi = bf16_rne(wval);
                    whi[ct][c][e] = (short)hi;
                    wlo[ct][c][e] = (short)bf16_rne(wval - bf16_f32(hi));
                }
            }
        }
    }
    float4 bo = *(const float4*)(b_out + NVW * w);
    __syncthreads();

    const int srow = tid >> 5;         // staging row [0,16)
    const int sslt = tid & 31;         // staging chunk slot
    const int rb = tid >> 5, jb = tid & 31;   // reduce mapping: batch, col
    const int ar = lane & 15, acg = lane >> 4;  // A-frag row / k-group

    for (int t = 0; t < SEQ; ++t) {
        // ---- inter-WG barrier: all of group's flags >= t ----
        if (t > 0) {
            if (tid < 64) {
                int guard = 0;
                while (guard < (1 << 24)) {
                    int v = cloadi(flg + (tid & 31));
                    if (__all(v >= t)) break;
                    __builtin_amdgcn_s_sleep(1);
                    ++guard;
                }
            }
            __syncthreads();
        }

        // ---- stage h_t (bf16 hi/lo) into LDS; 16B chunk c stored at c^(row&7) ----
        float e2p;
        if (t == 0) {
#pragma unroll
            for (int i = 0; i < 4; ++i) {
                int c = i * 32 + sslt;
                const float* p = h0 + (size_t)(b0 + srow) * HIDDEN + c * 8;
                short8_t h8, l8;
#pragma unroll
                for (int e = 0; e < 8; ++e) {
                    float vv = p[e];
                    unsigned short hi = bf16_rne(vv);
                    h8[e] = (short)hi;
                    l8[e] = (short)bf16_rne(vv - bf16_f32(hi));
                }
                int cs = (c ^ (srow & 7)) << 3;
                *(short8_t*)(sHi + srow * 1024 + cs) = h8;
                *(short8_t*)(sLo + srow * 1024 + cs) = l8;
            }
            e2p = E2[(size_t)sX[rb * SEQ + t] * HIDDEN + j0 + jb];
        } else {
            const unsigned short* srcH = hpHi + (size_t)((t - 1) & 1) * BATCH * HIDDEN
                                              + (size_t)(b0 + srow) * HIDDEN;
            const unsigned short* srcL = hpLo + (size_t)((t - 1) & 1) * BATCH * HIDDEN
                                              + (size_t)(b0 + srow) * HIDDEN;
            uint4 th[4], tl[4];
#pragma unroll
            for (int i = 0; i < 4; ++i) {
                int c = i * 32 + sslt;
                th[i] = cload4u(srcH + c * 8);
                tl[i] = cload4u(srcL + c * 8);
            }
            e2p = E2[(size_t)sX[rb * SEQ + t] * HIDDEN + j0 + jb];   // prefetch under MALL latency
            WAITVM0();
            __builtin_amdgcn_sched_barrier(0);
#pragma unroll
            for (int i = 0; i < 4; ++i) {
                int c = i * 32 + sslt;
                int cs = (c ^ (srow & 7)) << 3;
                *(uint4*)(sHi + srow * 1024 + cs) = th[i];
                *(uint4*)(sLo + srow * 1024 + cs) = tl[i];
            }
        }
        __syncthreads();

        // ---- MFMA phase: C[16b x 32j] += h[16 x 128k] * W[128k x 32j] per wave ----
        f32x4 acc0 = {0.f, 0.f, 0.f, 0.f};
        f32x4 acc1 = {0.f, 0.f, 0.f, 0.f};
#pragma unroll
        for (int c = 0; c < 4; ++c) {
            int c8 = wv * 16 + c * 4 + acg;          // logical 16B chunk of row ar
            int off = ar * 1024 + ((c8 ^ (ar & 7)) << 3);
            short8_t ahi = *(const short8_t*)(sHi + off);
            short8_t alo = *(const short8_t*)(sLo + off);
            acc0 = __builtin_amdgcn_mfma_f32_16x16x32_bf16(ahi, whi[0][c], acc0, 0, 0, 0);
            acc1 = __builtin_amdgcn_mfma_f32_16x16x32_bf16(ahi, whi[1][c], acc1, 0, 0, 0);
            acc0 = __builtin_amdgcn_mfma_f32_16x16x32_bf16(alo, whi[0][c], acc0, 0, 0, 0);
            acc1 = __builtin_amdgcn_mfma_f32_16x16x32_bf16(alo, whi[1][c], acc1, 0, 0, 0);
            acc0 = __builtin_amdgcn_mfma_f32_16x16x32_bf16(ahi, wlo[0][c], acc0, 0, 0, 0);
            acc1 = __builtin_amdgcn_mfma_f32_16x16x32_bf16(ahi, wlo[1][c], acc1, 0, 0, 0);
        }
        // C layout: col=lane&15, row=(lane>>4)*4+q  -> sPart[wv][row][col(+16*ct)]
#pragma unroll
        for (int q = 0; q < 4; ++q) {
            sPart[wv * 512 + (acg * 4 + q) * 32 + ar]      = acc0[q];
            sPart[wv * 512 + (acg * 4 + q) * 32 + 16 + ar] = acc1[q];
        }
        __syncthreads();

        // ---- reduce 8 wave-partials + E2 + tanh; coherent bf16 hi/lo store ----
        {
            float s = 0.f;
#pragma unroll
            for (int z = 0; z < 8; ++z) s += sPart[z * 512 + tid];
            float hn = tanhf(s + e2p);
            unsigned short hi = bf16_rne(hn);
            unsigned short lo = bf16_rne(hn - bf16_f32(hi));
            size_t di = (size_t)(t & 1) * BATCH * HIDDEN + (size_t)(b0 + rb) * HIDDEN + j0 + jb;
            cstore_short(hpHi + di, hi);
            cstore_short(hpLo + di, lo);
            if (t == SEQ - 1)
                hf[(size_t)(b0 + rb) * HIDDEN + j0 + jb] = hn;
        }
        WAITVM0();
        __syncthreads();
        if (tid == 0)
            asm volatile("global_store_dword %0, %1, off sc0 sc1" :: "v"(flg + w), "v"(t + 1) : "memory");

        // ---- fused logits for position t-1 (off the critical path) ----
        if (t > 0) {
            const short* hRow = sHi + rb * 1024;
            const short* lRow = sLo + rb * 1024;
            int bx = rb & 7;
            float a0 = 0.f, a1 = 0.f, a2 = 0.f, a3 = 0.f;
#pragma unroll
            for (int m = 0; m < 4; ++m) {
                int c = jb + 32 * m;                 // logical chunk (8 k each)
                int cs = (c ^ bx) << 3;
                short8_t h8 = *(const short8_t*)(hRow + cs);
                short8_t l8 = *(const short8_t*)(lRow + cs);
                const float* w0 = WoT + (size_t)(NVW * w + 0) * HIDDEN + c * 8;
                const float* w1 = WoT + (size_t)(NVW * w + 1) * HIDDEN + c * 8;
                const float* w2 = WoT + (size_t)(NVW * w + 2) * HIDDEN + c * 8;
                const float* w3 = WoT + (size_t)(NVW * w + 3) * HIDDEN + c * 8;
#pragma unroll
                for (int e = 0; e < 8; ++e) {
                    float hv = bf16_f32((unsigned short)h8[e]) + bf16_f32((unsigned short)l8[e]);
                    a0 += hv * w0[e];
                    a1 += hv * w1[e];
                    a2 += hv * w2[e];
                    a3 += hv * w3[e];
                }
            }
#pragma unroll
            for (int off = 1; off < 32; off <<= 1) {
                a0 += __shfl_xor(a0, off);
                a1 += __shfl_xor(a1, off);
                a2 += __shfl_xor(a2, off);
                a3 += __shfl_xor(a3, off);
            }
            if (jb == 0) {
                float4 out4 = make_float4(a0 + bo.x, a1 + bo.y, a2 + bo.z, a3 + bo.w);
                *(float4*)(logits + ((size_t)(b0 + rb) * SEQ + (t - 1)) * VOCAB + NVW * w) = out4;
            }
        }
    }

    // ---- epilogue: logits for t = SEQ-1 from h_SEQ ----
    if (tid < 64) {
        int guard = 0;
        while (guard < (1 << 24)) {
            int v = cloadi(flg + (tid & 31));
            if (__all(v >= SEQ)) break;
            __builtin_amdgcn_s_sleep(1);
            ++guard;
        }
    }
    __syncthreads();
    {
        const unsigned short* srcH = hpHi + (size_t)((SEQ - 1) & 1) * BATCH * HIDDEN
                                          + (size_t)(b0 + srow) * HIDDEN;
        const unsigned short* srcL = hpLo + (size_t)((SEQ - 1) & 1) * BATCH * HIDDEN
                                          + (size_t)(b0 + srow) * HIDDEN;
#pragma unroll
        for (int i = 0; i < 4; ++i) {
            int c = i * 32 + sslt;
            uint4 th = cload4u(srcH + c * 8);
            uint4 tl = cload4u(srcL + c * 8);
            WAITVM0();
            int cs = (c ^ (srow & 7)) << 3;
            *(uint4*)(sHi + srow * 1024 + cs) = th;
            *(uint4*)(sLo + srow * 1024 + cs) = tl;
        }
    }
    __syncthreads();
    {
        const short* hRow = sHi + rb * 1024;
        const short* lRow = sLo + rb * 1024;
        int bx = rb & 7;
        float a0 = 0.f, a1 = 0.f, a2 = 0.f, a3 = 0.f;
#pragma unroll
        for (int m = 0; m < 4; ++m) {
            int c = jb + 32 * m;
            int cs = (c ^ bx) << 3;
            short8_t h8 = *(const short8_t*)(hRow + cs);
            short8_t l8 = *(const short8_t*)(lRow + cs);
            const float* w0 = WoT + (size_t)(NVW * w + 0) * HIDDEN + c * 8;
            const float* w1 = WoT + (size_t)(NVW * w + 1) * HIDDEN + c * 8;
            const float* w2 = WoT + (size_t)(NVW * w + 2) * HIDDEN + c * 8;
            const float* w3 = WoT + (size_t)(NVW * w + 3) * HIDDEN + c * 8;
#pragma unroll
            for (int e = 0; e < 8; ++e) {
                float hv = bf16_f32((unsigned short)h8[e]) + bf16_f32((unsigned short)l8[e]);
                a0 += hv * w0[e];
                a1 += hv * w1[e];
                a2 += hv * w2[e];
                a3 += hv * w3[e];
            }
        }
#pragma unroll
        for (int off = 1; off < 32; off <<= 1) {
            a0 += __shfl_xor(a0, off);
            a1 += __shfl_xor(a1, off);
            a2 += __shfl_xor(a2, off);
            a3 += __shfl_xor(a3, off);
        }
        if (jb == 0) {
            float4 out4 = make_float4(a0 + bo.x, a1 + bo.y, a2 + bo.z, a3 + bo.w);
            *(float4*)(logits + ((size_t)(b0 + rb) * SEQ + (SEQ - 1)) * VOCAB + NVW * w) = out4;
        }
    }
}

extern "C" void kernel_launch(void* const* d_in, const int* in_sizes, int n_in,
                              void* d_out, int out_size, void* d_ws, size_t ws_size,
                              hipStream_t stream) {
    (void)in_sizes; (void)n_in; (void)out_size; (void)ws_size;
    const int*   x     = (const int*)  d_in[0];
    const float* h0    = (const float*)d_in[1];
    const float* emb   = (const float*)d_in[2];
    const float* W_hx  = (const float*)d_in[3];
    const float* b_hx  = (const float*)d_in[4];
    const float* W_hh  = (const float*)d_in[5];
    const float* W_out = (const float*)d_in[6];
    const float* b_out = (const float*)d_in[7];

    float* logits = (float*)d_out;
    float* hf     = logits + (size_t)BATCH * SEQ * VOCAB;

    float* ws  = (float*)d_ws;
    float* E2  = ws + E2_OFF;
    float* WoT = ws + WOT_OFF;
    unsigned short* hpHi = (unsigned short*)(ws + HPH_OFF);
    unsigned short* hpLo = (unsigned short*)(ws + HPL_OFF);
    int*   flags = (int*)(ws + FLG_OFF);

    hipMemsetAsync(flags, 0, NGROUP * 32 * sizeof(int), stream);
    e2_kernel<<<512, 256, 0, stream>>>(emb, W_hx, b_hx, E2);
    wot_kernel<<<128, 256, 0, stream>>>(W_out, WoT);

    hipFuncSetAttribute(reinterpret_cast<const void*>(rnn_kernel),
                        hipFuncAttributeMaxDynamicSharedMemorySize, 114688);
    rnn_kernel<<<NGROUP * NWG, NTHR, 114688, stream>>>(x, h0, W_hh, E2, WoT, b_out,
                                                       hpHi, hpLo, flags, logits, hf);
}